// Round 1
// baseline (433.824 us; speedup 1.0000x reference)
//
#include <hip/hip_runtime.h>

// One LANE per 16B chunk (two lanes cooperate on one 32B row of 8 floats).
//
// Rationale: the previous version (one thread per row, two dwordx4 at 32B
// per-lane stride) issues VMEM instructions whose 64 lanes touch 32
// half-utilized 64B lines each. Chunk-per-lane makes every load/store
// instruction unit-stride (64 lanes x 16B contiguous = 16 fully-utilized
// lines). The missing row half is fetched from lane^1 via __shfl_xor
// (compiles to v_mov_b32_dpp quad_perm:[1,0,3,2] -- 4 VALU ops, no LDS).
// Compute (19-comparator sort + softmax) is duplicated across the lane
// pair; kernel stays memory-bound (~80 VALU ops vs ~200 cyc/wave HBM share).
//
// midv = 4th-smallest (ascending index 3) == 5th-largest.
// mask = x > midv (strict top-4). out = softmax(x) * mask.
// 537 MB total HBM traffic, zero reuse -> non-temporal loads/stores.

typedef float f32x4 __attribute__((ext_vector_type(4)));

#define CMPSWAP(i, j)                      \
    {                                      \
        float lo_ = fminf(x[i], x[j]);     \
        float hi_ = fmaxf(x[i], x[j]);     \
        x[i] = lo_;                        \
        x[j] = hi_;                        \
    }

__global__ __launch_bounds__(256) void HNet3_topk_softmax_kernel(
    const f32x4* __restrict__ in, f32x4* __restrict__ out, int nchunks)
{
    int g = blockIdx.x * blockDim.x + threadIdx.x;
    if (g >= nchunks) return;

    // Perfectly coalesced: lane i of the wave reads bytes [16i, 16i+16).
    f32x4 mine = __builtin_nontemporal_load(in + g);

    // Partner lane holds the other half of my row (pairs never straddle a
    // wave: chunks are consecutive, rows are chunk pairs, blockDim % 64 == 0).
    f32x4 other;
#pragma unroll
    for (int i = 0; i < 4; ++i) other[i] = __shfl_xor(mine[i], 1);

    const bool second = (g & 1);  // am I the high half of the row?

    float v[8];
#pragma unroll
    for (int i = 0; i < 4; ++i) {
        v[i]     = second ? other[i] : mine[i];
        v[i + 4] = second ? mine[i]  : other[i];
    }

    float x[8];
#pragma unroll
    for (int i = 0; i < 8; ++i) x[i] = v[i];

    // Optimal 8-element sorting network (19 comparators).
    CMPSWAP(0, 1) CMPSWAP(2, 3) CMPSWAP(4, 5) CMPSWAP(6, 7)
    CMPSWAP(0, 2) CMPSWAP(1, 3) CMPSWAP(4, 6) CMPSWAP(5, 7)
    CMPSWAP(1, 2) CMPSWAP(5, 6) CMPSWAP(0, 4) CMPSWAP(3, 7)
    CMPSWAP(1, 5) CMPSWAP(2, 6)
    CMPSWAP(1, 4) CMPSWAP(3, 6)
    CMPSWAP(2, 4) CMPSWAP(3, 5)
    CMPSWAP(3, 4)

    float midv = x[3];  // 4th-smallest == 5th-largest
    float m    = x[7];  // row max (free from the sort) for stable softmax

    float e[8];
    float s = 0.f;
#pragma unroll
    for (int i = 0; i < 8; ++i) {
        e[i] = __expf(v[i] - m);
        s += e[i];
    }
    float inv = __builtin_amdgcn_rcpf(s);  // v_rcp_f32, ~1 ulp

    float r[8];
#pragma unroll
    for (int i = 0; i < 8; ++i) r[i] = (v[i] > midv) ? e[i] * inv : 0.f;

    // My own 16B chunk of the output, unit-stride across lanes.
    f32x4 o;
#pragma unroll
    for (int i = 0; i < 4; ++i) o[i] = second ? r[i + 4] : r[i];

    __builtin_nontemporal_store(o, out + g);
}

extern "C" void kernel_launch(void* const* d_in, const int* in_sizes, int n_in,
                              void* d_out, int out_size, void* d_ws, size_t ws_size,
                              hipStream_t stream) {
    const f32x4* in = (const f32x4*)d_in[0];
    f32x4* out      = (f32x4*)d_out;

    // num_per_group is fixed at 8; one lane per f32x4 chunk (2 chunks/row).
    int nchunks = in_sizes[0] / 4;
    int threads = 256;
    int blocks  = (nchunks + threads - 1) / threads;

    HNet3_topk_softmax_kernel<<<blocks, threads, 0, stream>>>(in, out, nchunks);
}

// Round 2
// 430.225 us; speedup vs baseline: 1.0084x; 1.0084x over previous
//
#include <hip/hip_runtime.h>

// One thread per TWO rows of 8 floats (rows r and r+nrows/2, i.e. one row
// from each half of the array so each stream keeps the proven dense
// 2KB-per-wave access pattern of the 423us baseline).
//
// Round-1 A/B showed per-instruction coalescing is NOT the bottleneck
// (perfectly coalesced chunk-per-lane regressed 423->434us). Remaining
// residual vs the 85us copy ceiling is latency-hiding: this version doubles
// per-thread MLP (4 independent nontemporal loads in flight vs 2) and
// halves the wave count (smaller launch/drain tail). Traffic and per-row
// VALU work are unchanged.
//
// midv = 4th-smallest (ascending index 3) == 5th-largest.
// mask = x > midv (strict top-4). out = softmax(x) * mask.
// 537 MB total HBM traffic, zero reuse -> non-temporal loads/stores.

typedef float f32x4 __attribute__((ext_vector_type(4)));

#define CMPSWAP(i, j)                      \
    {                                      \
        float lo_ = fminf(x[i], x[j]);     \
        float hi_ = fmaxf(x[i], x[j]);     \
        x[i] = lo_;                        \
        x[j] = hi_;                        \
    }

__device__ __forceinline__ void process_row(const f32x4& a, const f32x4& b,
                                            f32x4& oa, f32x4& ob)
{
    float v[8] = {a[0], a[1], a[2], a[3], b[0], b[1], b[2], b[3]};
    float x[8];
#pragma unroll
    for (int i = 0; i < 8; ++i) x[i] = v[i];

    // Optimal 8-element sorting network (19 comparators).
    CMPSWAP(0, 1) CMPSWAP(2, 3) CMPSWAP(4, 5) CMPSWAP(6, 7)
    CMPSWAP(0, 2) CMPSWAP(1, 3) CMPSWAP(4, 6) CMPSWAP(5, 7)
    CMPSWAP(1, 2) CMPSWAP(5, 6) CMPSWAP(0, 4) CMPSWAP(3, 7)
    CMPSWAP(1, 5) CMPSWAP(2, 6)
    CMPSWAP(1, 4) CMPSWAP(3, 6)
    CMPSWAP(2, 4) CMPSWAP(3, 5)
    CMPSWAP(3, 4)

    float midv = x[3];  // 4th-smallest == 5th-largest
    float m    = x[7];  // row max (free from the sort) for stable softmax

    float e[8];
    float s = 0.f;
#pragma unroll
    for (int i = 0; i < 8; ++i) {
        e[i] = __expf(v[i] - m);
        s += e[i];
    }
    float inv = __builtin_amdgcn_rcpf(s);  // v_rcp_f32, ~1 ulp

    oa[0] = (v[0] > midv) ? e[0] * inv : 0.f;
    oa[1] = (v[1] > midv) ? e[1] * inv : 0.f;
    oa[2] = (v[2] > midv) ? e[2] * inv : 0.f;
    oa[3] = (v[3] > midv) ? e[3] * inv : 0.f;
    ob[0] = (v[4] > midv) ? e[4] * inv : 0.f;
    ob[1] = (v[5] > midv) ? e[5] * inv : 0.f;
    ob[2] = (v[6] > midv) ? e[6] * inv : 0.f;
    ob[3] = (v[7] > midv) ? e[7] * inv : 0.f;
}

__global__ __launch_bounds__(256) void HNet3_topk_softmax_kernel(
    const f32x4* __restrict__ in, f32x4* __restrict__ out, int nrows)
{
    const int half = (nrows + 1) >> 1;
    int r0 = blockIdx.x * blockDim.x + threadIdx.x;
    if (r0 >= half) return;
    int r1 = r0 + half;

    // Issue all independent nontemporal loads up front (4 in flight).
    f32x4 a0 = __builtin_nontemporal_load(in + 2 * r0);
    f32x4 b0 = __builtin_nontemporal_load(in + 2 * r0 + 1);
    f32x4 a1, b1;
    const bool have2 = (r1 < nrows);
    if (have2) {
        a1 = __builtin_nontemporal_load(in + 2 * r1);
        b1 = __builtin_nontemporal_load(in + 2 * r1 + 1);
    }

    f32x4 oa, ob;
    process_row(a0, b0, oa, ob);
    __builtin_nontemporal_store(oa, out + 2 * r0);
    __builtin_nontemporal_store(ob, out + 2 * r0 + 1);

    if (have2) {
        process_row(a1, b1, oa, ob);
        __builtin_nontemporal_store(oa, out + 2 * r1);
        __builtin_nontemporal_store(ob, out + 2 * r1 + 1);
    }
}

extern "C" void kernel_launch(void* const* d_in, const int* in_sizes, int n_in,
                              void* d_out, int out_size, void* d_ws, size_t ws_size,
                              hipStream_t stream) {
    const f32x4* in = (const f32x4*)d_in[0];
    f32x4* out      = (f32x4*)d_out;

    // num_per_group is fixed at 8 in setup_inputs(); kernel hardcodes it.
    int nrows   = in_sizes[0] / 8;
    int half    = (nrows + 1) >> 1;
    int threads = 256;
    int blocks  = (half + threads - 1) / threads;

    HNet3_topk_softmax_kernel<<<blocks, threads, 0, stream>>>(in, out, nrows);
}